// Round 5
// baseline (162.176 us; speedup 1.0000x reference)
//
#include <hip/hip_runtime.h>
#include <math.h>

// AutoregressiveFlowLayer MI355X — round 14.
// R13 post-mortem (53us, NEUTRAL): barrier-merge bought nothing -> barriers were
// not the limiter. Counters pin two real causes: (1) residency quantization —
// grid 1024 = 4 blocks/CU but LDS 49.6KB (and launch_bounds 6) cap at 3/CU ->
// makespan 2x block-span, occupancy ~45% as measured; (2) the scattered 4B
// gather (FETCH 65-70MB vs ~42MB useful = line overfetch) sits on the interval
// critical path (R13 even put issue+store in the same interval).
// R14 = SPLIT KERNELS:
//  - gather_xg: idx partitions a permutation of D -> gather is a row-permute.
//    Streams inputs coalesced via LDS rowbuf, writes fp16 xg[r][b][j] to
//    workspace (16.8MB). Pure roofline ~10us.
//  - main: NO scattered loads, NO xgh/xgf LDS. P1 B-frag = coalesced
//    global_load_dwordx4 from xg (lane->row 16ni+l16, col q*8 => contiguous
//    1KB/frag); epilogue x-pair = 4B L2-hit load. LDS 49.6->39.0KB and
//    __launch_bounds__(512,8): 4 blocks/CU, grid 1024 = exactly 4/CU, all
//    resident. Single barrier per tile (R13 structure minus gather).
// Kept: fp16 single-plane MFMA, weights=A frags in registers, dual-scratch
// weight staging, red_all + single tail store.

#define RR 32
#define DD 1024
#define BB 8192
#define HH 128
#define OO 64
#define TROWS 32
#define TILES_PER_BLOCK 8
#define BLOCKS_PER_R 32
#define GROWS 8        // rows per gather block

#define SHP 136   // u16 stride, h planes [row][feat] (bank-balanced)
#define SSC 136   // u16 scratch stride (weight staging, [col][k])

typedef _Float16 f16x8_t __attribute__((ext_vector_type(8)));
typedef float f32x4_t __attribute__((ext_vector_type(4)));
typedef unsigned short u16;
typedef unsigned int u32;

__device__ __forceinline__ u16 f16b(float x) {
    _Float16 h = (_Float16)x;            // v_cvt_f16_f32, RNE
    union { _Float16 f; u16 u; } c; c.f = h; return c.u;
}
__device__ __forceinline__ f32x4_t mfma16h(f16x8_t a, f16x8_t b, f32x4_t c) {
    return __builtin_amdgcn_mfma_f32_16x16x32_f16(a, b, c, 0, 0, 0);
}

// ---------------- gather kernel: xg[r][b][j] = fp16(inputs[b, idx[r,j]] * v) ----
__global__ __launch_bounds__(256, 8)
void gather_xg(const float* __restrict__ inputs,
               const int* __restrict__ idx,
               const int* __restrict__ valid,
               u16* __restrict__ xg)
{
    __shared__ float rowbuf[DD];          // 4KB
    __shared__ int   idx_s[RR * 32];      // 4KB
    __shared__ float v_s[RR * 32];        // 4KB
    const int tid = threadIdx.x;
    for (int i = tid; i < RR * 32; i += 256) {
        idx_s[i] = idx[i];
        v_s[i]   = valid[i] ? 1.f : 0.f;
    }
    const int b0 = blockIdx.x * GROWS;
    const int f  = tid * 4;
    const int r  = f >> 5, j = f & 31;
    for (int rr = 0; rr < GROWS; ++rr) {
        const int b = b0 + rr;
        __syncthreads();   // rowbuf reuse (and first-iter idx_s ready)
        *(float4*)&rowbuf[tid * 4] = *(const float4*)&inputs[b * DD + tid * 4];
        __syncthreads();
        ushort4 o;
        o.x = f16b(rowbuf[idx_s[f + 0]] * v_s[f + 0]);
        o.y = f16b(rowbuf[idx_s[f + 1]] * v_s[f + 1]);
        o.z = f16b(rowbuf[idx_s[f + 2]] * v_s[f + 2]);
        o.w = f16b(rowbuf[idx_s[f + 3]] * v_s[f + 3]);
        *(ushort4*)&xg[(size_t)r * (BB * 32) + (size_t)b * 32 + j] = o;
    }
}

// stage [K x 32] weight slice (row-major [k][col], ld ldc, col offset c0) into
// fp16 [col][k] scratch, conflict-free 4x4 transpose. tid in [0,256).
__device__ __forceinline__ void stage_block16(const float* __restrict__ W,
                                              const int* __restrict__ M,
                                              int ldc, int c0, int K, u16* dst,
                                              int tid)
{
    const int kb = tid >> 3;
    const int cb = tid & 7;
    if (kb * 4 >= K) return;
    const int k0 = kb * 4;
    float e[4][4];
#pragma unroll
    for (int i = 0; i < 4; ++i) {
        const int o = ((k0 + i) * ldc + c0 + 4 * cb) >> 2;
        float4 w = ((const float4*)W)[o];
        int4   m = ((const int4*)M)[o];
        e[i][0] = m.x ? w.x : 0.f; e[i][1] = m.y ? w.y : 0.f;
        e[i][2] = m.z ? w.z : 0.f; e[i][3] = m.w ? w.w : 0.f;
    }
#pragma unroll
    for (int j = 0; j < 4; ++j) {
        ushort4 p;
        p.x = f16b(e[0][j]); p.y = f16b(e[1][j]);
        p.z = f16b(e[2][j]); p.w = f16b(e[3][j]);
        *(ushort4*)&dst[(4 * cb + j) * SSC + k0] = p;
    }
}

// ReLU + fp16 pack of 4 accumulator values, one 8B store.
__device__ __forceinline__ void relu_store16(u16* __restrict__ dst, int o, f32x4_t a)
{
    ushort4 s;
    s.x = f16b(fmaxf(a[0], 0.f));
    s.y = f16b(fmaxf(a[1], 0.f));
    s.z = f16b(fmaxf(a[2], 0.f));
    s.w = f16b(fmaxf(a[3], 0.f));
    *(ushort4*)&dst[o] = s;
}

__global__ __launch_bounds__(512, 8)
void made_flow_r14(const u16* __restrict__ xg,
                   const float* __restrict__ W1,
                   const float* __restrict__ W2,
                   const float* __restrict__ Wout,
                   const int* __restrict__ valid,
                   const int* __restrict__ M1,
                   const int* __restrict__ M2,
                   const int* __restrict__ Mout,
                   float* __restrict__ out)
{
    __shared__ __align__(16) u16 h1s[2][TROWS * SHP];   // 17408 B (also staging scratch)
    __shared__ __align__(16) u16 h2s[2][TROWS * SHP];   // 17408 B
    __shared__ __align__(16) float red_all[TILES_PER_BLOCK][TROWS][4];  // 4096 B
    __shared__ float v_s[RR];

    u16* const scr  = h1s[0];
    u16* const scr2 = h1s[1];

    const int tid  = threadIdx.x;
    const int r    = blockIdx.x / BLOCKS_PER_R;
    const int rb   = blockIdx.x % BLOCKS_PER_R;
    const int lane = tid & 63;
    const int wave = tid >> 6;     // 0..7
    const int q    = lane >> 4;
    const int l16  = lane & 15;
    const int wm3  = wave & 3;     // P3: o-col group 16*wm3
    const int ni3  = wave >> 2;    // P3: batch-row half

    if (tid < RR) v_s[tid] = valid[r * RR + tid] ? 1.f : 0.f;

    // block's slice of the pre-gathered xg plane: rows rb*T*32 .., 32 fp16 cols
    const u16* const xgp = xg + (size_t)r * (BB * 32)
                              + (size_t)(rb * TILES_PER_BLOCK * TROWS) * 32;

    // ---- stage all weights -> per-wave fp16 register A-frags (W^T) via dual scratch ----
    f16x8_t a1;        // W1^T: wave cols 16w+l16, k=q*8..
    f16x8_t a2[4];     // W2^T: [ks], wave cols 16w+l16
    f16x8_t ao[4];     // Wout^T: cols 16*wm3+l16, [ks]
    {
        const float* W1r = W1 + r * RR * HH;   const int* M1r = M1 + r * RR * HH;
        const float* W2r = W2 + r * HH * HH;   const int* M2r = M2 + r * HH * HH;
        const float* Wor = Wout + r * HH * OO; const int* Mor = Mout + r * HH * OO;
        const int c = wave >> 1, h = wave & 1;
        for (int i = 0; i < 2; ++i) {
            __syncthreads();
            if (tid < 256) stage_block16(W2r, M2r, HH, 32 * (2 * i),     HH, scr,  tid);
            else           stage_block16(W2r, M2r, HH, 32 * (2 * i + 1), HH, scr2, tid - 256);
            __syncthreads();
            if (c == 2 * i) {
#pragma unroll
                for (int ks = 0; ks < 4; ++ks)
                    a2[ks] = *(const f16x8_t*)&scr[(16 * h + l16) * SSC + ks * 32 + q * 8];
            } else if (c == 2 * i + 1) {
#pragma unroll
                for (int ks = 0; ks < 4; ++ks)
                    a2[ks] = *(const f16x8_t*)&scr2[(16 * h + l16) * SSC + ks * 32 + q * 8];
            }
        }
        {
            __syncthreads();
            if (tid < 256) stage_block16(Wor, Mor, OO, 0,  HH, scr,  tid);
            else           stage_block16(Wor, Mor, OO, 32, HH, scr2, tid - 256);
            __syncthreads();
            const u16* s = (wm3 >> 1) ? scr2 : scr;
#pragma unroll
            for (int ks = 0; ks < 4; ++ks)
                ao[ks] = *(const f16x8_t*)&s[(16 * (wm3 & 1) + l16) * SSC + ks * 32 + q * 8];
        }
        for (int i = 0; i < 2; ++i) {
            __syncthreads();
            if (tid < 256) stage_block16(W1r, M1r, HH, 32 * (2 * i),     RR, scr,  tid);
            else           stage_block16(W1r, M1r, HH, 32 * (2 * i + 1), RR, scr2, tid - 256);
            __syncthreads();
            if (c == 2 * i)          a1 = *(const f16x8_t*)&scr [(16 * h + l16) * SSC + q * 8];
            else if (c == 2 * i + 1) a1 = *(const f16x8_t*)&scr2[(16 * h + l16) * SSC + q * 8];
        }
    }
    __syncthreads();   // scratch reads done before h1 writes

    const f32x4_t zero4 = {0.f, 0.f, 0.f, 0.f};

    // ---- prologue: P1(0) -> h1s[0] (B-frags straight from global xg) ----
    {
#pragma unroll
        for (int ni = 0; ni < 2; ++ni) {
            f16x8_t b = *(const f16x8_t*)&xgp[(16 * ni + l16) * 32 + q * 8];
            f32x4_t a = mfma16h(a1, b, zero4);
            relu_store16(h1s[0], (16 * ni + l16) * SHP + 16 * wave + 4 * q, a);
        }
    }

    // ---- main loop: ONE barrier per tile ----
    for (int t = 0; t <= TILES_PER_BLOCK; ++t) {
        __syncthreads();

        const bool doP2  = (t < TILES_PER_BLOCK);
        const bool doP3  = (t >= 1);
        const bool doP1n = (t + 1 < TILES_PER_BLOCK);

        // issue global loads first: P1(t+1) B-frags + epilogue(t-1) x-pair
        f16x8_t b1[2];
        if (doP1n) {
            const u16* xb = xgp + (size_t)((t + 1) * TROWS) * 32;
#pragma unroll
            for (int ni = 0; ni < 2; ++ni)
                b1[ni] = *(const f16x8_t*)&xb[(16 * ni + l16) * 32 + q * 8];
        }
        const int j0  = 8 * wm3 + 2 * q;
        const int row = 16 * ni3 + l16;
        u32 xw = 0;
        if (doP3)
            xw = *(const u32*)&xgp[(size_t)((t - 1) * TROWS + row) * 32 + j0];

        // P3(t-1): out^T = Wout^T @ h2^T; wave (wm3,ni3): o=16*wm3+4q+i
        f32x4_t acc3 = zero4;
        if (doP3) {
            const u16* h2b = h2s[(t - 1) & 1];
#pragma unroll
            for (int ks = 0; ks < 4; ++ks) {
                f16x8_t b = *(const f16x8_t*)&h2b[(16 * ni3 + l16) * SHP + ks * 32 + q * 8];
                acc3 = mfma16h(ao[ks], b, acc3);
            }
        }

        // P2(t): h2^T = W2^T @ h1^T (wave owns 16 of M=128 cols, both ni, K=128)
        if (doP2) {
            const u16* h1b = h1s[t & 1];
            u16*       h2b = h2s[t & 1];
            f32x4_t acc[2] = {zero4, zero4};
#pragma unroll
            for (int ks = 0; ks < 4; ++ks) {
#pragma unroll
                for (int ni = 0; ni < 2; ++ni) {
                    f16x8_t b = *(const f16x8_t*)&h1b[(16 * ni + l16) * SHP + ks * 32 + q * 8];
                    acc[ni] = mfma16h(a2[ks], b, acc[ni]);
                }
            }
#pragma unroll
            for (int ni = 0; ni < 2; ++ni)
                relu_store16(h2b, (16 * ni + l16) * SHP + 16 * wave + 4 * q, acc[ni]);
        }

        // P1(t+1): h1^T = W1^T @ xg^T (frags already in registers)
        if (doP1n) {
            u16* h1b = h1s[(t + 1) & 1];
#pragma unroll
            for (int ni = 0; ni < 2; ++ni) {
                f32x4_t a = mfma16h(a1, b1[ni], zero4);
                relu_store16(h1b, (16 * ni + l16) * SHP + 16 * wave + 4 * q, a);
            }
        }

        // epilogue(t-1): acc3[i]: i even=shift(j), i odd=log_s(j), j=8*wm3+2q+(i>>1)
        if (doP3) {
            const float vj0 = v_s[j0], vj1 = v_s[j0 + 1];
            union { u32 u; _Float16 h[2]; } xc; xc.u = xw;
            const float xv0 = (float)xc.h[0], xv1 = (float)xc.h[1];
            const float u0 = (xv0 - acc3[0]) * __expf(-acc3[1]);
            const float u1 = (xv1 - acc3[2]) * __expf(-acc3[3]);
            float p = (-0.5f * u0 * u0 - 0.91893853320467266954f - acc3[1]) * vj0
                    + (-0.5f * u1 * u1 - 0.91893853320467266954f - acc3[3]) * vj1;
            p += __shfl_xor(p, 16, 64);
            p += __shfl_xor(p, 32, 64);
            if (q == 0) red_all[t - 1][row][wm3] = p;
        }
    }

    // ---- tail: reduce red_all across wm3, single batched global store ----
    __syncthreads();
    if (tid < TILES_PER_BLOCK * TROWS) {
        const int tt  = tid >> 5;      // 0..7
        const int row = tid & 31;
        float4 rv = *(const float4*)&red_all[tt][row][0];
        out[((rb * TILES_PER_BLOCK + tt) * TROWS + row) * RR + r] =
            rv.x + rv.y + rv.z + rv.w;
    }
}

extern "C" void kernel_launch(void* const* d_in, const int* in_sizes, int n_in,
                              void* d_out, int out_size, void* d_ws, size_t ws_size,
                              hipStream_t stream)
{
    const float* inputs = (const float*)d_in[0];
    const float* W1     = (const float*)d_in[1];
    const float* W2     = (const float*)d_in[2];
    const float* Wout   = (const float*)d_in[3];
    const int*   idx    = (const int*)d_in[4];
    const int*   valid  = (const int*)d_in[5];
    const int*   M1     = (const int*)d_in[6];
    const int*   M2     = (const int*)d_in[7];
    const int*   Mout   = (const int*)d_in[8];
    float*       out    = (float*)d_out;
    u16*         xg     = (u16*)d_ws;   // 32 * 8192 * 32 * 2B = 16.8 MB

    hipLaunchKernelGGL(gather_xg, dim3(BB / GROWS), dim3(256), 0, stream,
                       inputs, idx, valid, xg);
    hipLaunchKernelGGL(made_flow_r14, dim3(RR * BLOCKS_PER_R), dim3(512), 0, stream,
                       xg, W1, W2, Wout, valid, M1, M2, Mout, out);
}